// Round 4
// baseline (325.399 us; speedup 1.0000x reference)
//
#include <hip/hip_runtime.h>

#define TSEQ 2048
#define BB 4
#define CDIM 1024
#define NH 16
#define HD 64
#define MR (TSEQ*BB)   // 8192 rows
#define C2SCALE 0.045084220f   // log2(e)/sqrt(CDIM) = log2(e)/32

typedef __attribute__((ext_vector_type(8))) short sh8;   // 8 bf16 = 4 VGPRs
typedef __attribute__((ext_vector_type(4))) short sh4;   // 4 bf16
typedef __attribute__((ext_vector_type(4))) float f4;    // MFMA C/D
typedef __attribute__((ext_vector_type(4))) unsigned int u32x4;

__device__ __forceinline__ unsigned short f2bf(float x){
  unsigned u = __builtin_bit_cast(unsigned, x);
  u += 0x7fffu + ((u>>16)&1u);          // round-to-nearest-even
  return (unsigned short)(u>>16);
}

// pack two floats -> dword of 2 bf16 (lo = a, hi = b), single VALU op
__device__ __forceinline__ unsigned cvtpk(float a, float b){
  unsigned r;
  asm("v_cvt_pk_bf16_f32 %0, %1, %2" : "=v"(r) : "v"(a), "v"(b));
  return r;
}

__device__ __forceinline__ void gll16(const unsigned short* g, unsigned short* l){
  __builtin_amdgcn_global_load_lds(
      (const __attribute__((address_space(1))) unsigned int*)g,
      (__attribute__((address_space(3))) unsigned int*)l, 16, 0, 0);
}

// ---------------- fp32 -> bf16 conversion, fused ----------------
__global__ void conv_x(const float* __restrict__ a, const float* __restrict__ b,
                       unsigned short* __restrict__ ya, unsigned short* __restrict__ yb){
  const float* s = blockIdx.y ? b : a;
  unsigned short* d = blockIdx.y ? yb : ya;
  int i = (blockIdx.x*256 + threadIdx.x)*4;
  f4 v = *(const f4*)(s+i);
  sh4 o;
  o.x = (short)f2bf(v.x); o.y = (short)f2bf(v.y);
  o.z = (short)f2bf(v.z); o.w = (short)f2bf(v.w);
  *(sh4*)(d+i) = o;
}

__global__ void conv_w(const float* __restrict__ w0, const float* __restrict__ w1,
                       const float* __restrict__ w2, const float* __restrict__ w3,
                       unsigned short* __restrict__ y0, unsigned short* __restrict__ y1,
                       unsigned short* __restrict__ y2, unsigned short* __restrict__ y3){
  const float* s; unsigned short* d;
  switch(blockIdx.y){
    case 0: s=w0; d=y0; break;
    case 1: s=w1; d=y1; break;
    case 2: s=w2; d=y2; break;
    default: s=w3; d=y3; break;
  }
  int i = (blockIdx.x*256 + threadIdx.x)*4;
  f4 v = *(const f4*)(s+i);
  sh4 o;
  o.x = (short)f2bf(v.x); o.y = (short)f2bf(v.y);
  o.z = (short)f2bf(v.z); o.w = (short)f2bf(v.w);
  *(sh4*)(d+i) = o;
}

// ================= deep-pipelined GEMM core (round-4 geometry) =================
// BM=256, BN=128, BK=64, 256 threads = 4 waves (2M x 2N), per-wave 128x64.
// Round-4 change: per-wave tile 64x64 -> 128x64. FLOP/LDS-byte 32 -> 42.7 and
// 64 MFMA per barrier (was 32): round 2/3's core was LDS-read-bound (reads
// 128KB/CU/K-tile vs 307 MFMA-cy/SIMD). LDS forces 1 block/CU either way, so
// 4 waves + ~250 VGPR is free. 3-slot ring (3 x 48KB = 144KB), 2-tile-ahead
// prefetch (~1 tile of compute covers HBM latency), stages issued BEFORE the
// ds_reads (memory-op program order keeps gll16 early; MFMAs interleave via
// data deps). One vmcnt(12)+s_barrier per K-tile.
// Races (unchanged from verified round-3 flow): stage target slot (q+2)%3 was
// last read during tile kt-1, whose ds_reads completed (lgkm-waited before
// their MFMAs) ahead of tile kt-1's closing barrier; vmcnt(12) at tile end
// waits exactly tile kt+1's 12 loads (12 more for kt+2 are in flight).
#define NKT 16          // CDIM/64
#define BUFS 24576      // shorts per ring slot (A 256*64=16384 + B 128*64=8192)

__device__ __forceinline__ void gemm_core(
    const unsigned short* __restrict__ Aglob, const unsigned short* __restrict__ Bglob,
    unsigned short* smem, int m0, int n0, int tid, f4 (&acc)[8][4])
{
  const int wave = tid>>6, lane = tid&63;
  const int g = lane>>4, c = lane&15;
  const int wr = wave>>1, wc = wave&1;

  // staging bases: A slot i*256+tid (i<8) -> row i*32+(tid>>3), chunk (tid&7)
  // B slot i*256+tid (i<4) -> row i*32+(tid>>3). Source chunk pre-swizzled.
  const int srow = tid>>3, sch = tid&7;
  const unsigned short* aBase = Aglob + (size_t)(m0+srow)*CDIM + (sch^(srow&7))*8;
  const unsigned short* bBase = Bglob + (size_t)(n0+srow)*CDIM + (sch^(srow&7))*8;

  // prologue: stage tiles 0 and 1
#pragma unroll
  for (int i=0;i<8;i++) gll16(aBase + (size_t)i*32*CDIM,      smem + (i*256+tid)*8);
#pragma unroll
  for (int i=0;i<4;i++) gll16(bBase + (size_t)i*32*CDIM,      smem + 16384 + (i*256+tid)*8);
#pragma unroll
  for (int i=0;i<8;i++) gll16(aBase + (size_t)i*32*CDIM + 64, smem + BUFS + (i*256+tid)*8);
#pragma unroll
  for (int i=0;i<4;i++) gll16(bBase + (size_t)i*32*CDIM + 64, smem + BUFS + 16384 + (i*256+tid)*8);
  asm volatile("s_waitcnt vmcnt(12)" ::: "memory");   // tile 0 landed
  __builtin_amdgcn_s_barrier();

  const int arow = wr*128 + c;       // + mt*16
  const int brow = wc*64 + c;        // + nt*16
  const int ch0 = g ^ (c&7);         // ks=0 swizzled chunk
  const int ch1 = (4+g) ^ (c&7);     // ks=1

  int q = 0;
  for (int kt=0; kt<NKT; kt++){
    unsigned short* bufc = smem + q*BUFS;
    int rr = q+2; if (rr>=3) rr-=3;                 // stage target ring slot
    unsigned short* dst = smem + rr*BUFS;
    // ---- stage tile kt+2 first (loads fly across the whole compute) ----
    if (kt+2 < NKT){
      const size_t koff = (size_t)(kt+2)*64;
#pragma unroll
      for (int i=0;i<8;i++) gll16(aBase + (size_t)i*32*CDIM + koff, dst + (i*256+tid)*8);
#pragma unroll
      for (int i=0;i<4;i++) gll16(bBase + (size_t)i*32*CDIM + koff, dst + 16384 + (i*256+tid)*8);
    }
    // ---- fragment reads (24 x ds_read_b128) ----
    sh8 af[8][2], bfr[4][2];
#pragma unroll
    for (int mt=0;mt<8;mt++){
      af[mt][0] = *(const sh8*)(bufc + (arow+mt*16)*64 + ch0*8);
      af[mt][1] = *(const sh8*)(bufc + (arow+mt*16)*64 + ch1*8);
    }
#pragma unroll
    for (int nt=0;nt<4;nt++){
      bfr[nt][0] = *(const sh8*)(bufc + 16384 + (brow+nt*16)*64 + ch0*8);
      bfr[nt][1] = *(const sh8*)(bufc + 16384 + (brow+nt*16)*64 + ch1*8);
    }
    // ---- 64 MFMA ----
    __builtin_amdgcn_s_setprio(1);
#pragma unroll
    for (int mt=0;mt<8;mt++)
#pragma unroll
      for (int nt=0;nt<4;nt++){
        acc[mt][nt] = __builtin_amdgcn_mfma_f32_16x16x32_bf16(af[mt][0], bfr[nt][0], acc[mt][nt],0,0,0);
        acc[mt][nt] = __builtin_amdgcn_mfma_f32_16x16x32_bf16(af[mt][1], bfr[nt][1], acc[mt][nt],0,0,0);
      }
    __builtin_amdgcn_s_setprio(0);
    if (kt < NKT-1){
      if (kt < NKT-2) asm volatile("s_waitcnt vmcnt(12)" ::: "memory");  // tile kt+1 landed
      else            asm volatile("s_waitcnt vmcnt(0)" ::: "memory");   // tail drain
    }
    __builtin_amdgcn_s_barrier();
    q = (q==2)?0:q+1;
  }
}

// ---------------- final GEMM: C[m][n] = sum_k A[m][k]*W[n][k] + bias[n], fp32 out ----
__global__ __launch_bounds__(256,1) void gemm_u(
    const unsigned short* __restrict__ A, const unsigned short* __restrict__ Bw,
    const float* __restrict__ bias, float* __restrict__ Cout){
  __shared__ unsigned short smem[3*BUFS];
  const int tid  = threadIdx.x;
  const int wave = tid>>6, lane = tid&63;
  const int g = lane>>4, c = lane&15;
  const int m0 = blockIdx.x*256, n0 = blockIdx.y*128;
  const int wr = wave>>1, wc = wave&1;
  f4 acc[8][4] = {};
  gemm_core(A, Bw, smem, m0, n0, tid, acc);

#pragma unroll
  for (int nt=0; nt<4; nt++){
    int nn = n0 + wc*64 + nt*16 + c;
    float bsv = bias[nn];
#pragma unroll
    for (int mt=0; mt<8; mt++){
      int mb = m0 + wr*128 + mt*16 + 4*g;
#pragma unroll
      for (int r=0; r<4; r++)
        Cout[(size_t)(mb+r)*CDIM + nn] = acc[mt][nt][r] + bsv;
    }
  }
}

// ---------------- fused Q/K/V projection: blockIdx.z selects output ----------------
// z=0: Q = x1@Wq^T+bq, scaled by C2SCALE, bf16 row-major
// z=1: K = x2@Wk^T+bk, bf16 row-major
// z=2: V = x2@Wv^T+bv, bf16 transposed to (b,h,d,t)
__global__ __launch_bounds__(256,1) void gemm_qkv(
    const unsigned short* __restrict__ x1b, const unsigned short* __restrict__ x2b,
    const unsigned short* __restrict__ wq, const unsigned short* __restrict__ wk,
    const unsigned short* __restrict__ wv,
    const float* __restrict__ bq, const float* __restrict__ bk, const float* __restrict__ bv,
    unsigned short* __restrict__ Qo, unsigned short* __restrict__ Ko,
    unsigned short* __restrict__ Vo){
  __shared__ unsigned short smem[3*BUFS];
  const int z = blockIdx.z;
  const unsigned short* A  = (z==0) ? x1b : x2b;
  const unsigned short* Bw = (z==0) ? wq : (z==1) ? wk : wv;
  const float* bias        = (z==0) ? bq : (z==1) ? bk : bv;
  const int tid  = threadIdx.x;
  const int wave = tid>>6, lane = tid&63;
  const int g = lane>>4, c = lane&15;
  const int m0 = blockIdx.x*256, n0 = blockIdx.y*128;
  const int wr = wave>>1, wc = wave&1;
  f4 acc[8][4] = {};
  gemm_core(A, Bw, smem, m0, n0, tid, acc);

#pragma unroll
  for (int nt=0; nt<4; nt++){
    int nn = n0 + wc*64 + nt*16 + c;
    float bsv = bias[nn];
#pragma unroll
    for (int mt=0; mt<8; mt++){
      int mb = m0 + wr*128 + mt*16 + 4*g;
#pragma unroll
      for (int r=0; r<4; r++){
        float v = acc[mt][nt][r] + bsv;
        int mm = mb + r;
        if (z==0){
          Qo[(size_t)mm*CDIM + nn] = f2bf(v*C2SCALE);
        } else if (z==1){
          Ko[(size_t)mm*CDIM + nn] = f2bf(v);
        } else {
          int t = mm>>2, bb = mm&3, h = nn>>6, d = nn&63;
          Vo[(((size_t)bb*NH + h)*HD + d)*TSEQ + t] = f2bf(v);
        }
      }
    }
  }
}

// ---------------- flash attention, S^T / O^T -----------------------------------
// Round-4 change (VALU was the bottleneck: VALUBusy 53% > MfmaUtil 31%):
//  - pk2 (3 VALU) -> v_cvt_pk_bf16_f32 (1 VALU) for all bf16 packing
//  - lrun VALU adds + final shfl reduce removed: denominator computed by one
//    extra MFMA per pf with an all-ones A-fragment (D[.][q] = sum_k P[k][q],
//    identical across rows -> every lane already holds the full denominator)
__global__ __launch_bounds__(256,4) void attn_kernel(
    const unsigned short* __restrict__ Q, const unsigned short* __restrict__ Kb,
    const unsigned short* __restrict__ Vt, unsigned short* __restrict__ O){
  __shared__ unsigned short Ks[2][64*64];      // (key, d), chunk ^= row&7
  __shared__ unsigned short Vs[2][64*64];      // (d, key), chunk ^= d&7
  const int tid=threadIdx.x, wave=tid>>6, lane=tid&63;
  const int g=lane>>4, c=lane&15;
  const bool godd = (g&1);
  const int gx = blockIdx.x;                   // 1024 linear blocks
  const int bh = ((gx>>7)<<3) | (gx&7);        // all 16 qts of a bh share gx%8 (same XCD)
  const int qt = (gx>>3)&15;
  const int b = bh>>4, h = bh&15;
  const int qbase = qt*128 + wave*32;

  u32x4 onesw; onesw.x=0x3f803f80u; onesw.y=0x3f803f80u; onesw.z=0x3f803f80u; onesw.w=0x3f803f80u;
  const sh8 vones = __builtin_bit_cast(sh8, onesw);

  // staging bases: per thread 2 gll16 for K, 2 for V, per 64-key tile
  const unsigned short* kb0[2];
  const unsigned short* vb0[2];
#pragma unroll
  for (int i=0; i<2; i++){
    int cc = i*256+tid;
    int krow = cc>>3, kch = (cc&7) ^ (krow&7);
    kb0[i] = Kb + ((size_t)krow*BB + b)*CDIM + h*HD + kch*8;
    int vd = cc>>3, vch = (cc&7) ^ (vd&7);
    vb0[i] = Vt + ((size_t)(b*NH+h)*HD + vd)*TSEQ + vch*8;
  }

  sh8 qfr[2][2];
#pragma unroll
  for (int qf=0; qf<2; qf++)
#pragma unroll
    for (int kc=0; kc<2; kc++){
      int t = qbase + qf*16 + c;
      qfr[qf][kc] = *(const sh8*)(Q + ((size_t)t*BB + b)*CDIM + h*HD + kc*32 + g*8);
    }

  f4 oacc[4][2] = {};                          // O^T frags: [d-frag][q-frag]
  f4 dacc[2] = {};                             // denominator accumulators (per q-frag)

  // prologue: stage tile 0 into buffer 0
#pragma unroll
  for (int i=0; i<2; i++){
    gll16(kb0[i], Ks[0] + (i*256+tid)*8);
    gll16(vb0[i], Vs[0] + (i*256+tid)*8);
  }
  __syncthreads();                             // drains vmcnt(0): tile 0 resident

  const int NT = TSEQ/64;                      // 32 tiles
  int cur = 0;
  for (int it=0; it<NT; it++){
    // issue next tile's global->LDS loads into the idle buffer (in flight
    // during the compute below; __syncthreads at iter end drains them)
    if (it+1 < NT){
      int k0n = (it+1)*64;
#pragma unroll
      for (int i=0; i<2; i++){
        gll16(kb0[i] + (size_t)k0n*BB*CDIM, Ks[cur^1] + (i*256+tid)*8);
        gll16(vb0[i] + k0n,                 Vs[cur^1] + (i*256+tid)*8);
      }
    }
    const unsigned short* ks = Ks[cur];
    const unsigned short* vs = Vs[cur];

    // per 32-key group: S^T MFMA -> exp2 + in-register transpose -> PV MFMA
#pragma unroll
    for (int sub=0; sub<2; sub++){
      f4 sacc[2][2] = {};
      __builtin_amdgcn_s_setprio(1);
#pragma unroll
      for (int j=0; j<2; j++){
        int kf = sub*2 + j;
        sh8 af[2];
#pragma unroll
        for (int kc=0; kc<2; kc++){
          int ch = (kc*4+g) ^ (c&7);
          af[kc] = *(const sh8*)(ks + (kf*16+c)*64 + ch*8);
        }
#pragma unroll
        for (int kc=0; kc<2; kc++)
#pragma unroll
          for (int qf=0; qf<2; qf++)
            sacc[j][qf] = __builtin_amdgcn_mfma_f32_16x16x32_bf16(af[kc], qfr[qf][kc], sacc[j][qf],0,0,0);
      }
      __builtin_amdgcn_s_setprio(0);

      sh8 pf[2];
#pragma unroll
      for (int qf=0; qf<2; qf++){
        f4 sa = sacc[0][qf];
        f4 sb = sacc[1][qf];
        float pa0 = __builtin_amdgcn_exp2f(sa[0]);
        float pa1 = __builtin_amdgcn_exp2f(sa[1]);
        float pa2 = __builtin_amdgcn_exp2f(sa[2]);
        float pa3 = __builtin_amdgcn_exp2f(sa[3]);
        float pb0 = __builtin_amdgcn_exp2f(sb[0]);
        float pb1 = __builtin_amdgcn_exp2f(sb[1]);
        float pb2 = __builtin_amdgcn_exp2f(sb[2]);
        float pb3 = __builtin_amdgcn_exp2f(sb[3]);
        // dwords: low short = even key, high short = odd key
        unsigned A0 = cvtpk(pa0, pa1);   // keys 4g+{0,1} of kf=sub*2
        unsigned A1 = cvtpk(pa2, pa3);   // keys 4g+{2,3}
        unsigned B0 = cvtpk(pb0, pb1);   // keys 4g+{0,1} of kf=sub*2+1
        unsigned B1 = cvtpk(pb2, pb3);
        // exchange: A' = {A.lo32lanes ; B.lo32lanes}, B' = {A.hi ; B.hi}
        asm("v_permlane32_swap_b32 %0, %1" : "+v"(A0), "+v"(B0));
        asm("v_permlane32_swap_b32 %0, %1" : "+v"(A1), "+v"(B1));
        // g <-> g^1 movement (xor 16 within each 32-lane half)
        unsigned xA0 = (unsigned)__builtin_amdgcn_ds_swizzle((int)A0, 0x401F);
        unsigned xA1 = (unsigned)__builtin_amdgcn_ds_swizzle((int)A1, 0x401F);
        unsigned xB0 = (unsigned)__builtin_amdgcn_ds_swizzle((int)B0, 0x401F);
        unsigned xB1 = (unsigned)__builtin_amdgcn_ds_swizzle((int)B1, 0x401F);
        u32x4 pw;
        pw.x = godd ? xB0 : A0;   // keys g*8+{0,1}
        pw.y = godd ? xB1 : A1;   // keys g*8+{2,3}
        pw.z = godd ? B0  : xA0;  // keys g*8+{4,5}
        pw.w = godd ? B1  : xA1;  // keys g*8+{6,7}
        pf[qf] = __builtin_bit_cast(sh8, pw);
      }
      __builtin_amdgcn_s_setprio(1);
#pragma unroll
      for (int qf=0; qf<2; qf++)
        dacc[qf] = __builtin_amdgcn_mfma_f32_16x16x32_bf16(vones, pf[qf], dacc[qf],0,0,0);
#pragma unroll
      for (int df=0; df<4; df++){
        int ch = (sub*4+g) ^ (c&7);
        sh8 vf = *(const sh8*)(vs + (df*16+c)*64 + ch*8);
#pragma unroll
        for (int qf=0; qf<2; qf++)
          oacc[df][qf] = __builtin_amdgcn_mfma_f32_16x16x32_bf16(vf, pf[qf], oacc[df][qf],0,0,0);
      }
      __builtin_amdgcn_s_setprio(0);
    }

    __syncthreads();     // drains this wave's glls (vmcnt 0) + all waves done reading
    cur ^= 1;
  }

  // normalize + store (denominator already complete in every lane)
#pragma unroll
  for (int qf=0; qf<2; qf++){
    float inv = 1.0f/dacc[qf][0];
    int t = qbase + qf*16 + c;
#pragma unroll
    for (int df=0; df<4; df++){
      uint2 pr;
      pr.x = cvtpk(oacc[df][qf][0]*inv, oacc[df][qf][1]*inv);
      pr.y = cvtpk(oacc[df][qf][2]*inv, oacc[df][qf][3]*inv);
      *(uint2*)(O + ((size_t)b*TSEQ + t)*CDIM + h*HD + df*16 + 4*g) = pr;
    }
  }
}

extern "C" void kernel_launch(void* const* d_in, const int* in_sizes, int n_in,
                              void* d_out, int out_size, void* d_ws, size_t ws_size,
                              hipStream_t stream){
  (void)in_sizes; (void)n_in; (void)out_size; (void)ws_size;
  const float* x1 = (const float*)d_in[0];
  const float* x2 = (const float*)d_in[1];
  const float* Wq = (const float*)d_in[2];
  const float* bq = (const float*)d_in[3];
  const float* Wk = (const float*)d_in[4];
  const float* bk = (const float*)d_in[5];
  const float* Wv = (const float*)d_in[6];
  const float* bv = (const float*)d_in[7];
  const float* Wu = (const float*)d_in[8];
  const float* bu = (const float*)d_in[9];

  unsigned short* ws = (unsigned short*)d_ws;
  size_t o = 0;
  unsigned short* x1b = ws + o; o += (size_t)MR*CDIM;
  unsigned short* x2b = ws + o; o += (size_t)MR*CDIM;
  unsigned short* wqb = ws + o; o += (size_t)CDIM*CDIM;
  unsigned short* wkb = ws + o; o += (size_t)CDIM*CDIM;
  unsigned short* wvb = ws + o; o += (size_t)CDIM*CDIM;
  unsigned short* wub = ws + o; o += (size_t)CDIM*CDIM;
  unsigned short* Qb  = ws + o; o += (size_t)MR*CDIM;
  unsigned short* Kbf = ws + o; o += (size_t)MR*CDIM;
  unsigned short* Vtb = ws + o; o += (size_t)MR*CDIM;
  unsigned short* Ob  = x1b;   // x1b dead after QKV GEMM; reuse for attention output

  conv_x<<<dim3((MR*CDIM)/1024, 2),   256, 0, stream>>>(x1, x2, x1b, x2b);
  conv_w<<<dim3((CDIM*CDIM)/1024, 4), 256, 0, stream>>>(Wq, Wk, Wv, Wu, wqb, wkb, wvb, wub);

  gemm_qkv<<<dim3(MR/256, CDIM/128, 3), 256, 0, stream>>>(
      x1b, x2b, wqb, wkb, wvb, bq, bk, bv, Qb, Kbf, Vtb);
  attn_kernel<<<dim3(1024), 256, 0, stream>>>(Qb, Kbf, Vtb, Ob);
  gemm_u<<<dim3(MR/256, CDIM/128), 256, 0, stream>>>(Ob, wub, bu, (float*)d_out);
}

// Round 5
// 318.489 us; speedup vs baseline: 1.0217x; 1.0217x over previous
//
#include <hip/hip_runtime.h>

#define TSEQ 2048
#define BB 4
#define CDIM 1024
#define NH 16
#define HD 64
#define MR (TSEQ*BB)   // 8192 rows
#define C2SCALE 0.045084220f   // log2(e)/sqrt(CDIM) = log2(e)/32

typedef __attribute__((ext_vector_type(8))) short sh8;   // 8 bf16 = 4 VGPRs
typedef __attribute__((ext_vector_type(4))) short sh4;   // 4 bf16
typedef __attribute__((ext_vector_type(4))) float f4;    // MFMA C/D
typedef __attribute__((ext_vector_type(4))) unsigned int u32x4;

__device__ __forceinline__ unsigned short f2bf(float x){
  unsigned u = __builtin_bit_cast(unsigned, x);
  u += 0x7fffu + ((u>>16)&1u);          // round-to-nearest-even
  return (unsigned short)(u>>16);
}

// pack two floats -> dword of 2 bf16 (lo = a, hi = b), single VALU op
__device__ __forceinline__ unsigned cvtpk(float a, float b){
  unsigned r;
  asm("v_cvt_pk_bf16_f32 %0, %1, %2" : "=v"(r) : "v"(a), "v"(b));
  return r;
}

__device__ __forceinline__ void gll16(const unsigned short* g, unsigned short* l){
  __builtin_amdgcn_global_load_lds(
      (const __attribute__((address_space(1))) unsigned int*)g,
      (__attribute__((address_space(3))) unsigned int*)l, 16, 0, 0);
}

// ---------------- fp32 -> bf16 conversion, fused ----------------
__global__ void conv_x(const float* __restrict__ a, const float* __restrict__ b,
                       unsigned short* __restrict__ ya, unsigned short* __restrict__ yb){
  const float* s = blockIdx.y ? b : a;
  unsigned short* d = blockIdx.y ? yb : ya;
  int i = (blockIdx.x*256 + threadIdx.x)*4;
  f4 v = *(const f4*)(s+i);
  sh4 o;
  o.x = (short)f2bf(v.x); o.y = (short)f2bf(v.y);
  o.z = (short)f2bf(v.z); o.w = (short)f2bf(v.w);
  *(sh4*)(d+i) = o;
}

__global__ void conv_w(const float* __restrict__ w0, const float* __restrict__ w1,
                       const float* __restrict__ w2, const float* __restrict__ w3,
                       unsigned short* __restrict__ y0, unsigned short* __restrict__ y1,
                       unsigned short* __restrict__ y2, unsigned short* __restrict__ y3){
  const float* s; unsigned short* d;
  switch(blockIdx.y){
    case 0: s=w0; d=y0; break;
    case 1: s=w1; d=y1; break;
    case 2: s=w2; d=y2; break;
    default: s=w3; d=y3; break;
  }
  int i = (blockIdx.x*256 + threadIdx.x)*4;
  f4 v = *(const f4*)(s+i);
  sh4 o;
  o.x = (short)f2bf(v.x); o.y = (short)f2bf(v.y);
  o.z = (short)f2bf(v.z); o.w = (short)f2bf(v.w);
  *(sh4*)(d+i) = o;
}

// ================= deep-pipelined GEMM core (round-5 geometry) =================
// BM=256, BN=128, 256 threads = 4 waves (2M x 2N), per-wave 128x64 (kept from
// round 4: best ds_read:MFMA ratio 12:32). Round-5 change: round 4 ran 1 wave/
// SIMD (Occupancy 11%, MfmaUtil 19%) -- nothing to overlap latency with. Fix:
// staging quantum BK=32, ring slot = 24KB, 3-slot ring = 72KB -> 2 blocks/CU
// co-resident (144KB LDS, 2 waves/SIMD). One block's MFMA now covers the other
// block's stage/drain. 32 sub-tiles, prefetch 2 ahead, steady-state vmcnt(6)
// (never 0 until the tail). Swizzle for BK=32: chunk ch(0..3) XOR (row>>1)&3,
// applied on the pre-swizzled GLOBAL src (LDS dest linear, rule #21); read
// side uses (c>>1)&3 (wave-uniform residual). Enumeration over all 64 lanes:
// each 16B bank-quad is hit exactly 8x = the b128 minimum -> conflict-free.
// Ring races: iter s reads slot s%3 (landed: prior iter's vmcnt+barrier);
// stage s+2 writes slot (s-1)%3, whose reads finished before iter s-1's
// closing barrier (lgkm drained before their MFMAs).
#define NST 32          // CDIM/32 sub-tiles
#define SLOT 12288      // shorts per ring slot: A 256*32=8192 + B 128*32=4096

__device__ __forceinline__ void gemm_core(
    const unsigned short* __restrict__ Aglob, const unsigned short* __restrict__ Bglob,
    unsigned short* smem, int m0, int n0, int tid, f4 (&acc)[8][4])
{
  const int wave = tid>>6, lane = tid&63;
  const int g = lane>>4, c = lane&15;
  const int wr = wave>>1, wc = wave&1;

  // staging: A = 4 gll16/thread, B = 2 gll16/thread per sub-tile
  const unsigned short* aSrc[4]; int aOff[4];
  const unsigned short* bSrc[2]; int bOff[2];
#pragma unroll
  for (int i=0;i<4;i++){
    int slot = i*256+tid; int row = slot>>2, ch = slot&3;
    aSrc[i] = Aglob + (size_t)(m0+row)*CDIM + (ch ^ ((row>>1)&3))*8;
    aOff[i] = slot*8;
  }
#pragma unroll
  for (int i=0;i<2;i++){
    int slot = i*256+tid; int row = slot>>2, ch = slot&3;
    bSrc[i] = Bglob + (size_t)(n0+row)*CDIM + (ch ^ ((row>>1)&3))*8;
    bOff[i] = 8192 + slot*8;
  }
  // fragment read offsets (shorts)
  const int swz = (c>>1)&3;
  const int aro = (wr*128 + c)*32 + (g ^ swz)*8;        // + mt*512
  const int bro = 8192 + (wc*64 + c)*32 + (g ^ swz)*8;  // + nt*512

  // prologue: stage sub-tiles 0,1
#pragma unroll
  for (int i=0;i<4;i++) gll16(aSrc[i],    smem + aOff[i]);
#pragma unroll
  for (int i=0;i<2;i++) gll16(bSrc[i],    smem + bOff[i]);
#pragma unroll
  for (int i=0;i<4;i++) gll16(aSrc[i]+32, smem + SLOT + aOff[i]);
#pragma unroll
  for (int i=0;i<2;i++) gll16(bSrc[i]+32, smem + SLOT + bOff[i]);
  asm volatile("s_waitcnt vmcnt(6)" ::: "memory");   // sub-tile 0 landed
  __builtin_amdgcn_s_barrier();

  int q = 0;
  for (int s=0; s<NST; s++){
    unsigned short* bufc = smem + q*SLOT;
    int rr = q+2; if (rr>=3) rr-=3;
    unsigned short* dst = smem + rr*SLOT;
    // stage sub-tile s+2 (in flight across this whole compute phase)
    if (s+2 < NST){
      const int ko = (s+2)*32;
#pragma unroll
      for (int i=0;i<4;i++) gll16(aSrc[i]+ko, dst + aOff[i]);
#pragma unroll
      for (int i=0;i<2;i++) gll16(bSrc[i]+ko, dst + bOff[i]);
    }
    // fragment reads (12 x ds_read_b128)
    sh8 af[8], bfr[4];
#pragma unroll
    for (int mt=0;mt<8;mt++) af[mt]  = *(const sh8*)(bufc + aro + mt*512);
#pragma unroll
    for (int nt=0;nt<4;nt++) bfr[nt] = *(const sh8*)(bufc + bro + nt*512);
    // 32 MFMA
    __builtin_amdgcn_s_setprio(1);
#pragma unroll
    for (int mt=0;mt<8;mt++)
#pragma unroll
      for (int nt=0;nt<4;nt++)
        acc[mt][nt] = __builtin_amdgcn_mfma_f32_16x16x32_bf16(af[mt], bfr[nt], acc[mt][nt],0,0,0);
    __builtin_amdgcn_s_setprio(0);
    if (s < NST-2)       asm volatile("s_waitcnt vmcnt(6)" ::: "memory");  // s+1 landed
    else if (s == NST-2) asm volatile("s_waitcnt vmcnt(0)" ::: "memory");  // tail drain
    __builtin_amdgcn_s_barrier();
    q = (q==2)?0:q+1;
  }
}

// ---------------- final GEMM: C[m][n] = sum_k A[m][k]*W[n][k] + bias[n], fp32 out ----
__global__ __launch_bounds__(256,2) void gemm_u(
    const unsigned short* __restrict__ A, const unsigned short* __restrict__ Bw,
    const float* __restrict__ bias, float* __restrict__ Cout){
  __shared__ unsigned short smem[3*SLOT];
  const int tid  = threadIdx.x;
  const int wave = tid>>6, lane = tid&63;
  const int g = lane>>4, c = lane&15;
  const int m0 = blockIdx.x*256, n0 = blockIdx.y*128;
  const int wr = wave>>1, wc = wave&1;
  f4 acc[8][4] = {};
  gemm_core(A, Bw, smem, m0, n0, tid, acc);

#pragma unroll
  for (int nt=0; nt<4; nt++){
    int nn = n0 + wc*64 + nt*16 + c;
    float bsv = bias[nn];
#pragma unroll
    for (int mt=0; mt<8; mt++){
      int mb = m0 + wr*128 + mt*16 + 4*g;
#pragma unroll
      for (int r=0; r<4; r++)
        Cout[(size_t)(mb+r)*CDIM + nn] = acc[mt][nt][r] + bsv;
    }
  }
}

// ---------------- fused Q/K/V projection: blockIdx.z selects output ----------------
// z=0: Q = x1@Wq^T+bq, scaled by C2SCALE, bf16 row-major
// z=1: K = x2@Wk^T+bk, bf16 row-major
// z=2: V = x2@Wv^T+bv, bf16 transposed to (b,h,d,t)
__global__ __launch_bounds__(256,2) void gemm_qkv(
    const unsigned short* __restrict__ x1b, const unsigned short* __restrict__ x2b,
    const unsigned short* __restrict__ wq, const unsigned short* __restrict__ wk,
    const unsigned short* __restrict__ wv,
    const float* __restrict__ bq, const float* __restrict__ bk, const float* __restrict__ bv,
    unsigned short* __restrict__ Qo, unsigned short* __restrict__ Ko,
    unsigned short* __restrict__ Vo){
  __shared__ unsigned short smem[3*SLOT];
  const int z = blockIdx.z;
  const unsigned short* A  = (z==0) ? x1b : x2b;
  const unsigned short* Bw = (z==0) ? wq : (z==1) ? wk : wv;
  const float* bias        = (z==0) ? bq : (z==1) ? bk : bv;
  const int tid  = threadIdx.x;
  const int wave = tid>>6, lane = tid&63;
  const int g = lane>>4, c = lane&15;
  const int m0 = blockIdx.x*256, n0 = blockIdx.y*128;
  const int wr = wave>>1, wc = wave&1;
  f4 acc[8][4] = {};
  gemm_core(A, Bw, smem, m0, n0, tid, acc);

#pragma unroll
  for (int nt=0; nt<4; nt++){
    int nn = n0 + wc*64 + nt*16 + c;
    float bsv = bias[nn];
#pragma unroll
    for (int mt=0; mt<8; mt++){
      int mb = m0 + wr*128 + mt*16 + 4*g;
#pragma unroll
      for (int r=0; r<4; r++){
        float v = acc[mt][nt][r] + bsv;
        int mm = mb + r;
        if (z==0){
          Qo[(size_t)mm*CDIM + nn] = f2bf(v*C2SCALE);
        } else if (z==1){
          Ko[(size_t)mm*CDIM + nn] = f2bf(v);
        } else {
          int t = mm>>2, bb = mm&3, h = nn>>6, d = nn&63;
          Vo[(((size_t)bb*NH + h)*HD + d)*TSEQ + t] = f2bf(v);
        }
      }
    }
  }
}

// ---------------- flash attention, S^T / O^T -----------------------------------
// Round-5: denominator reverted to the round-3 lrun + shfl reduce (the round-4
// all-ones-MFMA denominator coincided with a suspected attn regression; the
// VALU saving was marginal). cvtpk (1-op pack) retained from round 4.
__global__ __launch_bounds__(256,4) void attn_kernel(
    const unsigned short* __restrict__ Q, const unsigned short* __restrict__ Kb,
    const unsigned short* __restrict__ Vt, unsigned short* __restrict__ O){
  __shared__ unsigned short Ks[2][64*64];      // (key, d), chunk ^= row&7
  __shared__ unsigned short Vs[2][64*64];      // (d, key), chunk ^= d&7
  const int tid=threadIdx.x, wave=tid>>6, lane=tid&63;
  const int g=lane>>4, c=lane&15;
  const bool godd = (g&1);
  const int gx = blockIdx.x;                   // 1024 linear blocks
  const int bh = ((gx>>7)<<3) | (gx&7);        // all 16 qts of a bh share gx%8 (same XCD)
  const int qt = (gx>>3)&15;
  const int b = bh>>4, h = bh&15;
  const int qbase = qt*128 + wave*32;

  // staging bases: per thread 2 gll16 for K, 2 for V, per 64-key tile
  const unsigned short* kb0[2];
  const unsigned short* vb0[2];
#pragma unroll
  for (int i=0; i<2; i++){
    int cc = i*256+tid;
    int krow = cc>>3, kch = (cc&7) ^ (krow&7);
    kb0[i] = Kb + ((size_t)krow*BB + b)*CDIM + h*HD + kch*8;
    int vd = cc>>3, vch = (cc&7) ^ (vd&7);
    vb0[i] = Vt + ((size_t)(b*NH+h)*HD + vd)*TSEQ + vch*8;
  }

  sh8 qfr[2][2];
#pragma unroll
  for (int qf=0; qf<2; qf++)
#pragma unroll
    for (int kc=0; kc<2; kc++){
      int t = qbase + qf*16 + c;
      qfr[qf][kc] = *(const sh8*)(Q + ((size_t)t*BB + b)*CDIM + h*HD + kc*32 + g*8);
    }

  f4 oacc[4][2] = {};                          // O^T frags: [d-frag][q-frag]
  float lrun[2] = {0.f, 0.f};                  // lane-local partial denominators

  // prologue: stage tile 0 into buffer 0
#pragma unroll
  for (int i=0; i<2; i++){
    gll16(kb0[i], Ks[0] + (i*256+tid)*8);
    gll16(vb0[i], Vs[0] + (i*256+tid)*8);
  }
  __syncthreads();                             // drains vmcnt(0): tile 0 resident

  const int NT = TSEQ/64;                      // 32 tiles
  int cur = 0;
  for (int it=0; it<NT; it++){
    // issue next tile's global->LDS loads into the idle buffer (in flight
    // during the compute below; __syncthreads at iter end drains them)
    if (it+1 < NT){
      int k0n = (it+1)*64;
#pragma unroll
      for (int i=0; i<2; i++){
        gll16(kb0[i] + (size_t)k0n*BB*CDIM, Ks[cur^1] + (i*256+tid)*8);
        gll16(vb0[i] + k0n,                 Vs[cur^1] + (i*256+tid)*8);
      }
    }
    const unsigned short* ks = Ks[cur];
    const unsigned short* vs = Vs[cur];

    // per 32-key group: S^T MFMA -> exp2 + in-register transpose -> PV MFMA
#pragma unroll
    for (int sub=0; sub<2; sub++){
      f4 sacc[2][2] = {};
      __builtin_amdgcn_s_setprio(1);
#pragma unroll
      for (int j=0; j<2; j++){
        int kf = sub*2 + j;
        sh8 af[2];
#pragma unroll
        for (int kc=0; kc<2; kc++){
          int ch = (kc*4+g) ^ (c&7);
          af[kc] = *(const sh8*)(ks + (kf*16+c)*64 + ch*8);
        }
#pragma unroll
        for (int kc=0; kc<2; kc++)
#pragma unroll
          for (int qf=0; qf<2; qf++)
            sacc[j][qf] = __builtin_amdgcn_mfma_f32_16x16x32_bf16(af[kc], qfr[qf][kc], sacc[j][qf],0,0,0);
      }
      __builtin_amdgcn_s_setprio(0);

      sh8 pf[2];
#pragma unroll
      for (int qf=0; qf<2; qf++){
        f4 sa = sacc[0][qf];
        f4 sb = sacc[1][qf];
        float pa0 = __builtin_amdgcn_exp2f(sa[0]);
        float pa1 = __builtin_amdgcn_exp2f(sa[1]);
        float pa2 = __builtin_amdgcn_exp2f(sa[2]);
        float pa3 = __builtin_amdgcn_exp2f(sa[3]);
        float pb0 = __builtin_amdgcn_exp2f(sb[0]);
        float pb1 = __builtin_amdgcn_exp2f(sb[1]);
        float pb2 = __builtin_amdgcn_exp2f(sb[2]);
        float pb3 = __builtin_amdgcn_exp2f(sb[3]);
        lrun[qf] += ((pa0+pa1)+(pa2+pa3)) + ((pb0+pb1)+(pb2+pb3));
        // dwords: low short = even key, high short = odd key
        unsigned A0 = cvtpk(pa0, pa1);   // keys 4g+{0,1} of kf=sub*2
        unsigned A1 = cvtpk(pa2, pa3);   // keys 4g+{2,3}
        unsigned B0 = cvtpk(pb0, pb1);   // keys 4g+{0,1} of kf=sub*2+1
        unsigned B1 = cvtpk(pb2, pb3);
        // exchange: A' = {A.lo32lanes ; B.lo32lanes}, B' = {A.hi ; B.hi}
        asm("v_permlane32_swap_b32 %0, %1" : "+v"(A0), "+v"(B0));
        asm("v_permlane32_swap_b32 %0, %1" : "+v"(A1), "+v"(B1));
        // g <-> g^1 movement (xor 16 within each 32-lane half)
        unsigned xA0 = (unsigned)__builtin_amdgcn_ds_swizzle((int)A0, 0x401F);
        unsigned xA1 = (unsigned)__builtin_amdgcn_ds_swizzle((int)A1, 0x401F);
        unsigned xB0 = (unsigned)__builtin_amdgcn_ds_swizzle((int)B0, 0x401F);
        unsigned xB1 = (unsigned)__builtin_amdgcn_ds_swizzle((int)B1, 0x401F);
        u32x4 pw;
        pw.x = godd ? xB0 : A0;   // keys g*8+{0,1}
        pw.y = godd ? xB1 : A1;   // keys g*8+{2,3}
        pw.z = godd ? B0  : xA0;  // keys g*8+{4,5}
        pw.w = godd ? B1  : xA1;  // keys g*8+{6,7}
        pf[qf] = __builtin_bit_cast(sh8, pw);
      }
      __builtin_amdgcn_s_setprio(1);
#pragma unroll
      for (int df=0; df<4; df++){
        int ch = (sub*4+g) ^ (c&7);
        sh8 vf = *(const sh8*)(vs + (df*16+c)*64 + ch*8);
#pragma unroll
        for (int qf=0; qf<2; qf++)
          oacc[df][qf] = __builtin_amdgcn_mfma_f32_16x16x32_bf16(vf, pf[qf], oacc[df][qf],0,0,0);
      }
      __builtin_amdgcn_s_setprio(0);
    }

    __syncthreads();     // drains this wave's glls (vmcnt 0) + all waves done reading
    cur ^= 1;
  }

  // cross-lane denominator reduction (over g groups), then normalize + store
#pragma unroll
  for (int qf=0; qf<2; qf++){
    lrun[qf] += __shfl_xor(lrun[qf], 16, 64);
    lrun[qf] += __shfl_xor(lrun[qf], 32, 64);
    float inv = 1.0f/lrun[qf];
    int t = qbase + qf*16 + c;
#pragma unroll
    for (int df=0; df<4; df++){
      uint2 pr;
      pr.x = cvtpk(oacc[df][qf][0]*inv, oacc[df][qf][1]*inv);
      pr.y = cvtpk(oacc[df][qf][2]*inv, oacc[df][qf][3]*inv);
      *(uint2*)(O + ((size_t)b*TSEQ + t)*CDIM + h*HD + df*16 + 4*g) = pr;
    }
  }
}

extern "C" void kernel_launch(void* const* d_in, const int* in_sizes, int n_in,
                              void* d_out, int out_size, void* d_ws, size_t ws_size,
                              hipStream_t stream){
  (void)in_sizes; (void)n_in; (void)out_size; (void)ws_size;
  const float* x1 = (const float*)d_in[0];
  const float* x2 = (const float*)d_in[1];
  const float* Wq = (const float*)d_in[2];
  const float* bq = (const float*)d_in[3];
  const float* Wk = (const float*)d_in[4];
  const float* bk = (const float*)d_in[5];
  const float* Wv = (const float*)d_in[6];
  const float* bv = (const float*)d_in[7];
  const float* Wu = (const float*)d_in[8];
  const float* bu = (const float*)d_in[9];

  unsigned short* ws = (unsigned short*)d_ws;
  size_t o = 0;
  unsigned short* x1b = ws + o; o += (size_t)MR*CDIM;
  unsigned short* x2b = ws + o; o += (size_t)MR*CDIM;
  unsigned short* wqb = ws + o; o += (size_t)CDIM*CDIM;
  unsigned short* wkb = ws + o; o += (size_t)CDIM*CDIM;
  unsigned short* wvb = ws + o; o += (size_t)CDIM*CDIM;
  unsigned short* wub = ws + o; o += (size_t)CDIM*CDIM;
  unsigned short* Qb  = ws + o; o += (size_t)MR*CDIM;
  unsigned short* Kbf = ws + o; o += (size_t)MR*CDIM;
  unsigned short* Vtb = ws + o; o += (size_t)MR*CDIM;
  unsigned short* Ob  = x1b;   // x1b dead after QKV GEMM; reuse for attention output

  conv_x<<<dim3((MR*CDIM)/1024, 2),   256, 0, stream>>>(x1, x2, x1b, x2b);
  conv_w<<<dim3((CDIM*CDIM)/1024, 4), 256, 0, stream>>>(Wq, Wk, Wv, Wu, wqb, wkb, wvb, wub);

  gemm_qkv<<<dim3(MR/256, CDIM/128, 3), 256, 0, stream>>>(
      x1b, x2b, wqb, wkb, wvb, bq, bk, bv, Qb, Kbf, Vtb);
  attn_kernel<<<dim3(1024), 256, 0, stream>>>(Qb, Kbf, Vtb, Ob);
  gemm_u<<<dim3(MR/256, CDIM/128), 256, 0, stream>>>(Ob, wub, bu, (float*)d_out);
}